// Round 1
// 160.086 us; speedup vs baseline: 1.0380x; 1.0380x over previous
//
#include <hip/hip_runtime.h>

// Problem: B=16, C=4, H=W=512. input [B,C,H,W] f32; target [B,C+1,H,W] f32,
// last channel a {0,1} mask. Output scalar:
//   (1/B) * sum_b [ cnt_b>0 ? sum_{c,hw} mask*(in-tg)^2 / (C*cnt_b) : 0 ]
//
// History: R1/R3/R5 all ~59-61 us at 2.65 TB/s delivered regardless of
// occupancy/pipelining. R4 DMA staging worse. R7 (prev best, 166.0 us
// harness headline): 3 streams/block, one channel per block, XCD-swizzled
// so the 4 c-blocks of a (b,chunk) unit share an L2 for mask re-reads,
// nontemporal in/tg loads.
// R8 (this round): rocprof top-5 shows partial kernel <49.4 us (all top
// slots are the harness's 335 MB ws-poison fill at 6.7 TB/s). Memory loop
// kept byte-identical; structural cleanup only: per-block slot writes
// instead of memset+atomicAdd (one fewer graph dispatch, no atomic
// round-trips, poison-safe since every slot read is written), and a
// parallel 256-thread final reduction instead of 1x64 serial.

#define BATCH 16
#define CHAN 4
#define HWPIX (512 * 512)                 // 262144 pixels per plane
#define CHUNK_PX 16384                    // pixels per chunk
#define CPB (HWPIX / CHUNK_PX)            // 16 chunks per plane
#define UNITS (BATCH * CPB)               // 256 (b,k) units
#define THREADS 256
#define TOTAL_BLOCKS (UNITS * CHAN)       // 1024 blocks
#define G4 (CHUNK_PX / 4)                 // 4096 float4 per chunk-plane
#define ITERS (G4 / THREADS)              // 16 iterations per thread

// ws layout: [0, 1024)        S slot per block  at b*64 + c*16 + k
//            [1024, 1024+256) cnt slot per unit at b*16 + k   (c==0 blocks)
#define WS_CNT_BASE (UNITS * CHAN)

typedef float vf4 __attribute__((ext_vector_type(4)));

__global__ __launch_bounds__(THREADS) void masked_mse_partial(
    const float* __restrict__ input,
    const float* __restrict__ target,
    float* __restrict__ ws) {
    // blockIdx swizzle: idx = q*32 + c*8 + r. All four c-blocks of unit
    // u=(q,r) are congruent mod 8 -> same XCD, dispatched within a 32-block
    // window -> mask chunk L2-hits on 3 of 4 reads.
    const int bid = blockIdx.x;
    const int r   = bid & 7;
    const int c   = (bid >> 3) & 3;
    const int q   = bid >> 5;
    const int u   = q * 8 + r;            // [0, 256)
    const int b   = u >> 4;               // u / CPB
    const int k   = u & (CPB - 1);

    const vf4* ip = (const vf4*)(input  + ((size_t)b * CHAN + c) * HWPIX
                                        + (size_t)k * CHUNK_PX);
    const vf4* tp = (const vf4*)(target + ((size_t)b * (CHAN + 1) + c) * HWPIX
                                        + (size_t)k * CHUNK_PX);
    const vf4* mp = (const vf4*)(target + ((size_t)b * (CHAN + 1) + CHAN) * HWPIX
                                        + (size_t)k * CHUNK_PX);

    float s = 0.f, cnt = 0.f;

    // 12 grouped loads (4 iters x 3 streams) before any use -> ~48 data
    // VGPRs live, deep MLP per wave. (Byte-identical to prev best.)
    for (int it = 0; it < ITERS; it += 4) {
        const int g0 = it * THREADS + threadIdx.x;
        vf4 a0 = __builtin_nontemporal_load(&ip[g0]);
        vf4 a1 = __builtin_nontemporal_load(&ip[g0 + THREADS]);
        vf4 a2 = __builtin_nontemporal_load(&ip[g0 + 2 * THREADS]);
        vf4 a3 = __builtin_nontemporal_load(&ip[g0 + 3 * THREADS]);
        vf4 t0 = __builtin_nontemporal_load(&tp[g0]);
        vf4 t1 = __builtin_nontemporal_load(&tp[g0 + THREADS]);
        vf4 t2 = __builtin_nontemporal_load(&tp[g0 + 2 * THREADS]);
        vf4 t3 = __builtin_nontemporal_load(&tp[g0 + 3 * THREADS]);
        vf4 m0 = mp[g0];
        vf4 m1 = mp[g0 + THREADS];
        vf4 m2 = mp[g0 + 2 * THREADS];
        vf4 m3 = mp[g0 + 3 * THREADS];

        vf4 d0 = a0 - t0, d1 = a1 - t1, d2 = a2 - t2, d3 = a3 - t3;
        vf4 acc = d0 * d0 * m0 + d1 * d1 * m1 + d2 * d2 * m2 + d3 * d3 * m3;
        s += acc.x + acc.y + acc.z + acc.w;

        if (c == 0) {   // wave-uniform: count mask once per (b,k) unit
            vf4 mc = m0 + m1 + m2 + m3;
            cnt += mc.x + mc.y + mc.z + mc.w;
        }
    }

    // wave-64 shuffle reduction
#pragma unroll
    for (int off = 32; off > 0; off >>= 1) {
        s   += __shfl_down(s, off, 64);
        cnt += __shfl_down(cnt, off, 64);
    }

    __shared__ float ss[THREADS / 64];
    __shared__ float sc[THREADS / 64];
    const int lane = threadIdx.x & 63;
    const int wid  = threadIdx.x >> 6;
    if (lane == 0) { ss[wid] = s; sc[wid] = cnt; }
    __syncthreads();

    if (threadIdx.x == 0) {
        float S = 0.f, Cn = 0.f;
#pragma unroll
        for (int w = 0; w < THREADS / 64; ++w) { S += ss[w]; Cn += sc[w]; }
        // unique slot per block -> no memset, no atomics, poison-safe
        ws[(b * CHAN + c) * CPB + k] = S;
        if (c == 0) ws[WS_CNT_BASE + b * CPB + k] = Cn;
    }
}

__global__ __launch_bounds__(256) void masked_mse_final(
    const float* __restrict__ ws,
    float* __restrict__ out) {
    // 256 threads = 16 groups of 16 lanes; group g handles batch b=g.
    // Each batch has 64 S slots (4 c * 16 k) and 16 cnt slots.
    const int t = threadIdx.x;
    const int g = t >> 4;                 // batch
    const int j = t & 15;

    float S = 0.f;
#pragma unroll
    for (int i = 0; i < 4; ++i) S += ws[g * 64 + j * 4 + i];
    float Cn = ws[WS_CNT_BASE + g * 16 + j];

    // reduce within each 16-lane group (all inside one wave-64)
#pragma unroll
    for (int off = 8; off > 0; off >>= 1) {
        S  += __shfl_down(S,  off, 16);
        Cn += __shfl_down(Cn, off, 16);
    }

    __shared__ float per_b[BATCH];
    if (j == 0) {
        float cb = Cn * (float)CHAN;      // C * #masked pixels
        per_b[g] = (cb > 0.f) ? (S / cb) : 0.f;
    }
    __syncthreads();

    if (t == 0) {
        float acc = 0.f;
#pragma unroll
        for (int b = 0; b < BATCH; ++b) acc += per_b[b];
        out[0] = acc / (float)BATCH;
    }
}

extern "C" void kernel_launch(void* const* d_in, const int* in_sizes, int n_in,
                              void* d_out, int out_size, void* d_ws, size_t ws_size,
                              hipStream_t stream) {
    const float* input  = (const float*)d_in[0];
    const float* target = (const float*)d_in[1];
    float* out = (float*)d_out;
    float* ws  = (float*)d_ws;

    masked_mse_partial<<<dim3(TOTAL_BLOCKS), dim3(THREADS), 0, stream>>>(
        input, target, ws);
    masked_mse_final<<<1, 256, 0, stream>>>(ws, out);
}

// Round 2
// 156.344 us; speedup vs baseline: 1.0628x; 1.0239x over previous
//
#include <hip/hip_runtime.h>

// Problem: B=16, C=4, H=W=512. input [B,C,H,W] f32; target [B,C+1,H,W] f32,
// last channel a {0,1} mask. Output scalar:
//   (1/B) * sum_b [ cnt_b>0 ? sum_{c,hw} mask*(in-tg)^2 / (C*cnt_b) : 0 ]
//
// History: R7 (166.0): 3 streams/block, one channel per block, XCD-swizzled
// mask reuse, nontemporal in/tg loads, memset+atomics. R8 (160.1): dropped
// memset node + atomics for per-block ws slots, parallel final reduce.
// rocprof: top-5 all harness ws-poison fills (6.7 TB/s); partial < 50 us.
// R9 (this round): occupancy attack. 1024 blocks = 4 blocks/CU was
// grid-limited at 16 waves/CU with ~48 live data VGPRs (>64 -> 4 waves/SIMD
// cap). Now: 2048 blocks (CHUNK 8192 px) = 8 blocks/CU, load-group depth
// halved (6 loads in flight, ~24 data VGPRs), __launch_bounds__(256,8)
// to hold VGPR <= 64 -> 32 waves/CU. Same bytes, same swizzle.

#define BATCH 16
#define CHAN 4
#define HWPIX (512 * 512)                 // 262144 pixels per plane
#define CHUNK_PX 8192                     // pixels per chunk
#define CPB (HWPIX / CHUNK_PX)            // 32 chunks per plane
#define UNITS (BATCH * CPB)               // 512 (b,k) units
#define THREADS 256
#define TOTAL_BLOCKS (UNITS * CHAN)       // 2048 blocks = 8 per CU
#define G4 (CHUNK_PX / 4)                 // 2048 float4 per chunk-plane
#define ITERS (G4 / THREADS)              // 8 iterations per thread

// ws layout: [0, 2048)        S slot per block  at (b*4 + c)*32 + k
//            [2048, 2048+512) cnt slot per unit at b*32 + k   (c==0 blocks)
#define WS_CNT_BASE (UNITS * CHAN)

typedef float vf4 __attribute__((ext_vector_type(4)));

__global__ __launch_bounds__(THREADS, 8) void masked_mse_partial(
    const float* __restrict__ input,
    const float* __restrict__ target,
    float* __restrict__ ws) {
    // blockIdx swizzle: idx = q*32 + c*8 + r. All four c-blocks of unit
    // u=(q,r) are congruent mod 8 -> same XCD, dispatched within a 32-block
    // window -> mask chunk L2-hits on 3 of 4 reads.
    const int bid = blockIdx.x;
    const int r   = bid & 7;
    const int c   = (bid >> 3) & 3;
    const int q   = bid >> 5;             // [0, 64)
    const int u   = q * 8 + r;            // [0, 512)
    const int b   = u >> 5;               // u / CPB
    const int k   = u & (CPB - 1);

    const vf4* ip = (const vf4*)(input  + ((size_t)b * CHAN + c) * HWPIX
                                        + (size_t)k * CHUNK_PX);
    const vf4* tp = (const vf4*)(target + ((size_t)b * (CHAN + 1) + c) * HWPIX
                                        + (size_t)k * CHUNK_PX);
    const vf4* mp = (const vf4*)(target + ((size_t)b * (CHAN + 1) + CHAN) * HWPIX
                                        + (size_t)k * CHUNK_PX);

    float s = 0.f, cnt = 0.f;

    // 6 grouped loads (2 iters x 3 streams) in flight -> ~24 data VGPRs,
    // VGPR <= 64 so 8 waves/SIMD resident. TLP does the latency hiding.
    for (int it = 0; it < ITERS; it += 2) {
        const int g0 = it * THREADS + threadIdx.x;
        vf4 a0 = __builtin_nontemporal_load(&ip[g0]);
        vf4 a1 = __builtin_nontemporal_load(&ip[g0 + THREADS]);
        vf4 t0 = __builtin_nontemporal_load(&tp[g0]);
        vf4 t1 = __builtin_nontemporal_load(&tp[g0 + THREADS]);
        vf4 m0 = mp[g0];
        vf4 m1 = mp[g0 + THREADS];

        vf4 d0 = a0 - t0, d1 = a1 - t1;
        vf4 acc = d0 * d0 * m0 + d1 * d1 * m1;
        s += acc.x + acc.y + acc.z + acc.w;

        if (c == 0) {   // wave-uniform: count mask once per (b,k) unit
            vf4 mc = m0 + m1;
            cnt += mc.x + mc.y + mc.z + mc.w;
        }
    }

    // wave-64 shuffle reduction
#pragma unroll
    for (int off = 32; off > 0; off >>= 1) {
        s   += __shfl_down(s, off, 64);
        cnt += __shfl_down(cnt, off, 64);
    }

    __shared__ float ss[THREADS / 64];
    __shared__ float sc[THREADS / 64];
    const int lane = threadIdx.x & 63;
    const int wid  = threadIdx.x >> 6;
    if (lane == 0) { ss[wid] = s; sc[wid] = cnt; }
    __syncthreads();

    if (threadIdx.x == 0) {
        float S = 0.f, Cn = 0.f;
#pragma unroll
        for (int w = 0; w < THREADS / 64; ++w) { S += ss[w]; Cn += sc[w]; }
        // unique slot per block -> no memset, no atomics, poison-safe
        ws[(b * CHAN + c) * CPB + k] = S;
        if (c == 0) ws[WS_CNT_BASE + b * CPB + k] = Cn;
    }
}

__global__ __launch_bounds__(256) void masked_mse_final(
    const float* __restrict__ ws,
    float* __restrict__ out) {
    // 256 threads = 16 groups of 16 lanes; group g handles batch b=g.
    // Each batch has 128 S slots (4 c * 32 k) and 32 cnt slots.
    const int t = threadIdx.x;
    const int g = t >> 4;                 // batch
    const int j = t & 15;

    float S = 0.f;
#pragma unroll
    for (int i = 0; i < 8; ++i) S += ws[g * 128 + j * 8 + i];
    float Cn = ws[WS_CNT_BASE + g * 32 + j * 2]
             + ws[WS_CNT_BASE + g * 32 + j * 2 + 1];

    // reduce within each 16-lane group (all inside one wave-64)
#pragma unroll
    for (int off = 8; off > 0; off >>= 1) {
        S  += __shfl_down(S,  off, 16);
        Cn += __shfl_down(Cn, off, 16);
    }

    __shared__ float per_b[BATCH];
    if (j == 0) {
        float cb = Cn * (float)CHAN;      // C * #masked pixels
        per_b[g] = (cb > 0.f) ? (S / cb) : 0.f;
    }
    __syncthreads();

    if (t == 0) {
        float acc = 0.f;
#pragma unroll
        for (int b = 0; b < BATCH; ++b) acc += per_b[b];
        out[0] = acc / (float)BATCH;
    }
}

extern "C" void kernel_launch(void* const* d_in, const int* in_sizes, int n_in,
                              void* d_out, int out_size, void* d_ws, size_t ws_size,
                              hipStream_t stream) {
    const float* input  = (const float*)d_in[0];
    const float* target = (const float*)d_in[1];
    float* out = (float*)d_out;
    float* ws  = (float*)d_ws;

    masked_mse_partial<<<dim3(TOTAL_BLOCKS), dim3(THREADS), 0, stream>>>(
        input, target, ws);
    masked_mse_final<<<1, 256, 0, stream>>>(ws, out);
}